// Round 4
// baseline (2218.680 us; speedup 1.0000x reference)
//
#include <hip/hip_runtime.h>
#include <hip/hip_bf16.h>
#include <hip/hip_fp16.h>
#include <math.h>

#define N_NODES 65536
#define N_EDGES 1048576
#define NB      32
#define D       64
#define NLAYERS 4
#define G       16     // dst nodes per edge-block
#define CH      64     // edges per chunk
#define AST     72     // ushort stride for bf16 LDS activation arrays (16B-aligned rows)
#define PST     68     // float stride for p / p*M overlay arrays
#define LOOFS   24576  // ushort offset of lo-plane in packed weights (per layer)
#define LSTRIDE 49152  // ushort stride per layer in packed weights

typedef __attribute__((ext_vector_type(8))) short short8;   // 8 bf16 in 4 VGPRs
typedef __attribute__((ext_vector_type(4))) float f32x4;

__device__ __forceinline__ float relu_f(float x){ return x > 0.f ? x : 0.f; }
__device__ __forceinline__ unsigned short bfbits(float x){
    __bf16 h = (__bf16)x;
    return __builtin_bit_cast(unsigned short, h);
}
__device__ __forceinline__ float bfval(float x){     // value after bf16 rounding
    __bf16 h = (__bf16)x;
    return (float)h;
}
__device__ __forceinline__ f32x4 mfma16(short8 a, short8 b, f32x4 c){
    return __builtin_amdgcn_mfma_f32_16x16x32_bf16(a, b, c, 0, 0, 0);
}

// ---------------- sort-by-dst machinery ----------------

__global__ void k_zero(int* __restrict__ p){
    p[blockIdx.x * 256 + threadIdx.x] = 0;
}

__global__ void k_hist(const int* __restrict__ dst, int* __restrict__ deg){
    int e = blockIdx.x * 256 + threadIdx.x;
    if (e < N_EDGES) atomicAdd(&deg[dst[e]], 1);
}

__global__ void k_scan1(const int* __restrict__ deg, int* __restrict__ part, int* __restrict__ bsum){
    __shared__ int s[256];
    int t = threadIdx.x;
    int i = blockIdx.x * 256 + t;
    int v = deg[i];
    s[t] = v; __syncthreads();
    for (int ofs = 1; ofs < 256; ofs <<= 1){
        int tv = (t >= ofs) ? s[t - ofs] : 0;
        __syncthreads();
        s[t] += tv;
        __syncthreads();
    }
    part[i] = s[t] - v;
    if (t == 255) bsum[blockIdx.x] = s[255];
}

__global__ void k_scan2(const int* __restrict__ bsum, int* __restrict__ bofs){
    __shared__ int s[256];
    int t = threadIdx.x;
    int v = bsum[t];
    s[t] = v; __syncthreads();
    for (int ofs = 1; ofs < 256; ofs <<= 1){
        int tv = (t >= ofs) ? s[t - ofs] : 0;
        __syncthreads();
        s[t] += tv;
        __syncthreads();
    }
    bofs[t] = s[t] - v;
}

__global__ void k_scan3(const int* __restrict__ part, const int* __restrict__ bofs,
                        int* __restrict__ off, int* __restrict__ cursor){
    int i = blockIdx.x * 256 + threadIdx.x;
    int o = part[i] + bofs[i >> 8];
    off[i] = o; cursor[i] = o;
    if (i == 0) off[N_NODES] = N_EDGES;
}

__global__ void k_scatter(const int* __restrict__ ei, const float* __restrict__ pos,
                          int* __restrict__ cursor, int* __restrict__ srcs,
                          float* __restrict__ pdb){
    int e = blockIdx.x * 256 + threadIdx.x;
    if (e >= N_EDGES) return;
    int s = ei[e], d = ei[N_EDGES + e];
    int p = atomicAdd(&cursor[d], 1);
    srcs[p]    = s;
    pdb[2*p]   = pos[2*d]   - pos[2*s];
    pdb[2*p+1] = pos[2*d+1] - pos[2*s+1];
}

// ---------------- weight pre-pack into MFMA B-fragment order (hi/lo) ----------------
// 6 matrices per layer: 0..2 = pW2,aW1,aW2 (edge kernel), 3..5 = Wl,Ws,Wd (node GEMM).
// Per layer: hi plane 24576 ushorts at [mat][nb][kf][lane][8], lo plane at +LOOFS.
// B-frag: lane holds B[k = kf*32 + (lane>>4)*8 + j][n = nb*16 + (lane&15)], j=0..7.

__global__ void k_pack(const float* __restrict__ pW2, const float* __restrict__ aW1,
                       const float* __restrict__ aW2, const float* __restrict__ Wl,
                       const float* __restrict__ Ws, const float* __restrict__ Wd,
                       unsigned short* __restrict__ bpk){
    int b  = blockIdx.x;                // L*48 + mat*8 + nb*2 + kf
    int kf = b & 1, nb = (b >> 1) & 3;
    int mat = (b >> 3) % 6, L = b / 48;
    int t = threadIdx.x;
    int lane = t & 63, jj = (t >> 6) * 2;
    const float* Wsel[6] = {pW2, aW1, aW2, Wl, Ws, Wd};
    const float* W = Wsel[mat] + (size_t)L * D * D;
    int n = nb * 16 + (lane & 15);
    unsigned short* dsthi = bpk + (size_t)L * LSTRIDE
                          + (((size_t)mat * 4 + nb) * 2 + kf) * 512 + lane * 8 + jj;
    #pragma unroll
    for (int u = 0; u < 2; ++u){
        int j = jj + u;
        int k = kf * 32 + (lane >> 4) * 8 + j;
        float w = W[k * D + n];
        float hv = bfval(w);
        dsthi[u]         = bfbits(w);
        dsthi[LOOFS + u] = bfbits(w - hv);
    }
}

// ---------------- shared MFMA tile: 64 rows (A in LDS hi/lo) x 16 cols (B frags) ----------------

__device__ __forceinline__ void gemm_tile(const unsigned short* __restrict__ Ah,
                                          const unsigned short* __restrict__ Al,
                                          const short8* Bh, const short8* Bl,
                                          int ln, int q, f32x4* accs)
{
    #pragma unroll
    for (int mt = 0; mt < 4; ++mt){
        int ro = (mt*16 + ln) * AST;
        short8 ah0 = __builtin_bit_cast(short8, *(const uint4*)(Ah + ro + q*8));
        short8 ah1 = __builtin_bit_cast(short8, *(const uint4*)(Ah + ro + 32 + q*8));
        short8 al0 = __builtin_bit_cast(short8, *(const uint4*)(Al + ro + q*8));
        short8 al1 = __builtin_bit_cast(short8, *(const uint4*)(Al + ro + 32 + q*8));
        f32x4 acc = {0.f, 0.f, 0.f, 0.f};
        acc = mfma16(ah0, Bh[0], acc);
        acc = mfma16(ah1, Bh[1], acc);
        acc = mfma16(al0, Bh[0], acc);
        acc = mfma16(al1, Bh[1], acc);
        acc = mfma16(ah0, Bl[0], acc);
        acc = mfma16(ah1, Bl[1], acc);
        accs[mt] = acc;
    }
}

// ---------------- node GEMM (MFMA): v/as (fp16) and ad (fp32) = h @ {Wl,Ws,Wd} ----------------

__global__ __launch_bounds__(256, 4) void k_nodegemm(
    const float* __restrict__ h, const unsigned short* __restrict__ bpkL,
    __half* __restrict__ v, __half* __restrict__ as_, float* __restrict__ ad)
{
    __shared__ __align__(16) unsigned short Hhi[64 * AST];
    __shared__ __align__(16) unsigned short Hlo[64 * AST];
    int row0 = blockIdx.x * 64;
    int t = threadIdx.x;
    {
        int r  = t >> 2;
        int kb = (t & 3) * 16;
        const float4* hp = (const float4*)(h + (size_t)(row0 + r) * D + kb);
        unsigned int hw[8], lw[8];
        #pragma unroll
        for (int i4 = 0; i4 < 4; ++i4){
            float4 a = hp[i4];
            float f[4] = {a.x, a.y, a.z, a.w};
            #pragma unroll
            for (int p = 0; p < 2; ++p){
                float f0 = f[p*2], f1 = f[p*2+1];
                unsigned short h0 = bfbits(f0), h1 = bfbits(f1);
                unsigned short l0 = bfbits(f0 - bfval(f0)), l1 = bfbits(f1 - bfval(f1));
                hw[i4*2 + p] = (unsigned int)h0 | ((unsigned int)h1 << 16);
                lw[i4*2 + p] = (unsigned int)l0 | ((unsigned int)l1 << 16);
            }
        }
        *(uint4*)&Hhi[r*AST + kb]     = make_uint4(hw[0], hw[1], hw[2], hw[3]);
        *(uint4*)&Hhi[r*AST + kb + 8] = make_uint4(hw[4], hw[5], hw[6], hw[7]);
        *(uint4*)&Hlo[r*AST + kb]     = make_uint4(lw[0], lw[1], lw[2], lw[3]);
        *(uint4*)&Hlo[r*AST + kb + 8] = make_uint4(lw[4], lw[5], lw[6], lw[7]);
    }
    __syncthreads();
    int w = t >> 6, lane = t & 63;
    int q = lane >> 4, ln = lane & 15;
    int c = w * 16 + ln;
    // persistent B fragments for mats 3..5 (Wl, Ws, Wd)
    short8 Bh[3][2], Bl[3][2];
    #pragma unroll
    for (int g = 0; g < 3; ++g)
        #pragma unroll
        for (int kf = 0; kf < 2; ++kf){
            int idx = (((g + 3)*4 + w)*2 + kf)*512 + lane*8;
            Bh[g][kf] = __builtin_bit_cast(short8, *(const uint4*)(bpkL + idx));
            Bl[g][kf] = __builtin_bit_cast(short8, *(const uint4*)(bpkL + LOOFS + idx));
        }
    f32x4 accs[4];
    // Wl -> v (fp16)
    gemm_tile(Hhi, Hlo, Bh[0], Bl[0], ln, q, accs);
    #pragma unroll
    for (int mt = 0; mt < 4; ++mt)
        #pragma unroll
        for (int r = 0; r < 4; ++r)
            v[(size_t)(row0 + mt*16 + q*4 + r) * D + c] = __float2half(accs[mt][r]);
    // Ws -> as (fp16)
    gemm_tile(Hhi, Hlo, Bh[1], Bl[1], ln, q, accs);
    #pragma unroll
    for (int mt = 0; mt < 4; ++mt)
        #pragma unroll
        for (int r = 0; r < 4; ++r)
            as_[(size_t)(row0 + mt*16 + q*4 + r) * D + c] = __float2half(accs[mt][r]);
    // Wd -> ad (fp32)
    gemm_tile(Hhi, Hlo, Bh[2], Bl[2], ln, q, accs);
    #pragma unroll
    for (int mt = 0; mt < 4; ++mt)
        #pragma unroll
        for (int r = 0; r < 4; ++r)
            ad[(size_t)(row0 + mt*16 + q*4 + r) * D + c] = accs[mt][r];
}

// ---------------- fused edge kernel (MFMA, split-bf16, fp16 gathers, 4 blocks/CU) ----------------

__global__ __launch_bounds__(256, 4) void k_edge(
    const int* __restrict__ off, const int* __restrict__ srcs, const float* __restrict__ pdb,
    const __half* __restrict__ vH, const __half* __restrict__ aH, const float* __restrict__ adF,
    const float* __restrict__ pW1, const float* __restrict__ pb1, const float* __restrict__ pb2,
    const float* __restrict__ ab1, const float* __restrict__ ab2,
    const unsigned short* __restrict__ bpkL,
    float* __restrict__ hout)
{
    __shared__ __align__(16) unsigned short ALDS[2 * 64 * AST]; // t1/t2 hi|lo ; pm f32 overlays
    __shared__ __align__(16) unsigned short ULDS[2 * 64 * AST]; // u hi|lo    ; p  f32 overlays
    __shared__ int s_sp[CH];      // src | (node-local l << 16)
    __shared__ int s_off[20];

    unsigned short* Ahi = ALDS;
    unsigned short* Alo = ALDS + 64 * AST;
    unsigned short* Uhi = ULDS;
    unsigned short* Ulo = ULDS + 64 * AST;
    float* Pf  = (float*)ULDS;    // p  (stride PST)
    float* PMf = (float*)ALDS;    // pm (stride PST)

    int t  = threadIdx.x;
    int n0 = blockIdx.x * G;
    if (t <= G) s_off[t] = off[n0 + t];
    __syncthreads();
    int e_begin = s_off[0], e_end = s_off[G];

    int w = t >> 6, lane = t & 63;
    int q = lane >> 4, ln = lane & 15;
    int c = w * 16 + ln;                // this wave's output-column slice

    // persistent per-wave B fragments (hi/lo) for mats 0..2 (pW2, aW1, aW2)
    short8 Bh[3][2], Bl[3][2];
    #pragma unroll
    for (int g = 0; g < 3; ++g)
        #pragma unroll
        for (int kf = 0; kf < 2; ++kf){
            int idx = ((g*4 + w)*2 + kf)*512 + lane*8;
            Bh[g][kf] = __builtin_bit_cast(short8, *(const uint4*)(bpkL + idx));
            Bl[g][kf] = __builtin_bit_cast(short8, *(const uint4*)(bpkL + LOOFS + idx));
        }
    float pb2c = pb2[c], ab1c = ab1[c], ab2c = ab2[c];

    float den[4] = {0.f, 0.f, 0.f, 0.f};
    float num[4] = {0.f, 0.f, 0.f, 0.f};

    for (int ec = e_begin; ec < e_end; ec += CH){
        int cnt = min(CH, e_end - ec);
        // ---- stage AB: edge metadata + t1 = relu(pd @ pW1 + pb1) -> Ahi/Alo [e][k]
        {
            int e = t & 63, kb = (t >> 6) * 16;
            int g = ec + ((e < cnt) ? e : 0);
            if (t < CH){
                int s = srcs[g];
                int l = 0;
                while (l < G-1 && g >= s_off[l+1]) ++l;
                s_sp[e] = s | (l << 16);
            }
            float p0 = pdb[2*g], p1 = pdb[2*g+1];
            unsigned int hw[8], lw[8];
            #pragma unroll
            for (int i2 = 0; i2 < 8; ++i2){
                int k = kb + i2*2;
                float f0 = relu_f(fmaf(p1, pW1[D + k],     fmaf(p0, pW1[k],     pb1[k])));
                float f1 = relu_f(fmaf(p1, pW1[D + k + 1], fmaf(p0, pW1[k + 1], pb1[k + 1])));
                unsigned short h0 = bfbits(f0), h1 = bfbits(f1);
                unsigned short l0 = bfbits(f0 - bfval(f0)), l1 = bfbits(f1 - bfval(f1));
                hw[i2] = (unsigned int)h0 | ((unsigned int)h1 << 16);
                lw[i2] = (unsigned int)l0 | ((unsigned int)l1 << 16);
            }
            *(uint4*)&Ahi[e*AST + kb]     = make_uint4(hw[0], hw[1], hw[2], hw[3]);
            *(uint4*)&Ahi[e*AST + kb + 8] = make_uint4(hw[4], hw[5], hw[6], hw[7]);
            *(uint4*)&Alo[e*AST + kb]     = make_uint4(lw[0], lw[1], lw[2], lw[3]);
            *(uint4*)&Alo[e*AST + kb + 8] = make_uint4(lw[4], lw[5], lw[6], lw[7]);
        }
        __syncthreads();
        // ---- stage C: prefetch fp16 gathers; GEMM1 -> delta; M in regs; u (bf16 hi/lo) -> ULDS
        float Mreg[16];
        {
            __half vg[16], ag[16];
            #pragma unroll
            for (int i = 0; i < 16; ++i){
                int e = (i >> 2)*16 + q*4 + (i & 3);
                int s = s_sp[e] & 0xFFFF;
                vg[i] = vH[(size_t)s * D + c];
                ag[i] = aH[(size_t)s * D + c];
            }
            f32x4 accs[4];
            gemm_tile(Ahi, Alo, Bh[0], Bl[0], ln, q, accs);
            #pragma unroll
            for (int mt = 0; mt < 4; ++mt){
                #pragma unroll
                for (int r = 0; r < 4; ++r){
                    int i = mt*4 + r;
                    int e = mt*16 + q*4 + r;
                    float dlt = relu_f(accs[mt][r] + pb2c);
                    int dn = n0 + (s_sp[e] >> 16);
                    float vv = __half2float(vg[i]);
                    float vs = __half2float(ag[i]);
                    float vd = adF[(size_t)dn * D + c];
                    Mreg[i] = vv + dlt;
                    float uu = vd - vs + dlt;
                    Uhi[e*AST + c] = bfbits(uu);
                    Ulo[e*AST + c] = bfbits(uu - bfval(uu));
                }
            }
        }
        __syncthreads();
        // ---- stage D: GEMM2 (u @ aW1) -> t2 -> Ahi/Alo (overwrite t1)
        {
            f32x4 accs[4];
            gemm_tile(Uhi, Ulo, Bh[1], Bl[1], ln, q, accs);
            #pragma unroll
            for (int mt = 0; mt < 4; ++mt){
                #pragma unroll
                for (int r = 0; r < 4; ++r){
                    int e = mt*16 + q*4 + r;
                    float t2 = relu_f(accs[mt][r] + ab1c);
                    Ahi[e*AST + c] = bfbits(t2);
                    Alo[e*AST + c] = bfbits(t2 - bfval(t2));
                }
            }
        }
        __syncthreads();
        // ---- stage E: GEMM3 (t2 @ aW2) -> alpha; p -> Pf; pm -> PMf (after mid-barrier)
        {
            f32x4 accs[4];
            gemm_tile(Ahi, Alo, Bh[2], Bl[2], ln, q, accs);
            #pragma unroll
            for (int mt = 0; mt < 4; ++mt){
                #pragma unroll
                for (int r = 0; r < 4; ++r){
                    int e = mt*16 + q*4 + r;
                    float a = relu_f(accs[mt][r] + ab2c);
                    float p = __expf(a);
                    accs[mt][r] = p;
                    Pf[e*PST + c] = p;
                }
            }
            __syncthreads();   // all waves done reading t2 (ALDS) as MFMA A-operand
            #pragma unroll
            for (int mt = 0; mt < 4; ++mt){
                #pragma unroll
                for (int r = 0; r < 4; ++r){
                    int e = mt*16 + q*4 + r;
                    PMf[e*PST + c] = accs[mt][r] * Mreg[mt*4 + r];
                }
            }
        }
        __syncthreads();
        // ---- stage F: per-node reduction (wave w owns nodes w*4..w*4+3, lane = channel)
        #pragma unroll
        for (int qn = 0; qn < 4; ++qn){
            int l  = w*4 + qn;
            int gs = max(s_off[l], ec);
            int ge = min(s_off[l+1], ec + cnt);
            float dd = den[qn], nn = num[qn];
            for (int g = gs; g < ge; ++g){
                int e = g - ec;
                dd += Pf [e*PST + lane];
                nn += PMf[e*PST + lane];
            }
            den[qn] = dd; num[qn] = nn;
        }
        __syncthreads();
    }
    #pragma unroll
    for (int qn = 0; qn < 4; ++qn){
        int n = n0 + w*4 + qn;
        hout[(size_t)n * D + lane] = num[qn] / den[qn];
    }
}

// ---------------- pooling + classifier ----------------

__global__ __launch_bounds__(256) void k_pool(const float* __restrict__ h,
                                              const float* __restrict__ outW,
                                              const float* __restrict__ outb,
                                              float* __restrict__ out)
{
    __shared__ float sm[4][64];
    __shared__ float sp[2][64];
    int b = blockIdx.x;
    int t = threadIdx.x, j = t & 63, g = t >> 6;
    float mx = -1e30f;
    for (int r = b*2048 + g; r < (b+1)*2048; r += 4)
        mx = fmaxf(mx, h[(size_t)r * D + j]);
    sm[g][j] = mx;
    __syncthreads();
    if (t < 64){
        float m = fmaxf(fmaxf(sm[0][j], sm[1][j]), fmaxf(sm[2][j], sm[3][j]));
        sp[0][j] = m * outW[j*2 + 0];
        sp[1][j] = m * outW[j*2 + 1];
    }
    __syncthreads();
    if (t == 0){
        float s0 = outb[0], s1 = outb[1];
        for (int k = 0; k < 64; ++k){ s0 += sp[0][k]; s1 += sp[1][k]; }
        out[b*2]   = s0;
        out[b*2+1] = s1;
    }
}

// ---------------- launch ----------------

extern "C" void kernel_launch(void* const* d_in, const int* in_sizes, int n_in,
                              void* d_out, int out_size, void* d_ws, size_t ws_size,
                              hipStream_t stream)
{
    const float* x    = (const float*)d_in[0];
    const float* pos  = (const float*)d_in[1];
    const float* Wl   = (const float*)d_in[2];
    const float* Ws   = (const float*)d_in[3];
    const float* Wd   = (const float*)d_in[4];
    const float* pW1  = (const float*)d_in[5];
    const float* pb1  = (const float*)d_in[6];
    const float* pW2  = (const float*)d_in[7];
    const float* pb2  = (const float*)d_in[8];
    const float* aW1  = (const float*)d_in[9];
    const float* ab1  = (const float*)d_in[10];
    const float* aW2  = (const float*)d_in[11];
    const float* ab2  = (const float*)d_in[12];
    const float* outW = (const float*)d_in[13];
    const float* outb = (const float*)d_in[14];
    const int*   ei   = (const int*)d_in[15];
    float* out = (float*)d_out;

    char* wp = (char*)d_ws;
    auto alloc = [&](size_t bytes){
        void* p = (void*)wp;
        wp += (bytes + 255) & ~(size_t)255;
        return p;
    };
    int*   deg    = (int*)  alloc((size_t)N_NODES * 4);
    int*   part   = (int*)  alloc((size_t)N_NODES * 4);
    int*   bsum   = (int*)  alloc(1024);
    int*   bofs   = (int*)  alloc(1024);
    int*   off    = (int*)  alloc((size_t)(N_NODES + 1) * 4);
    int*   cursor = (int*)  alloc((size_t)N_NODES * 4);
    int*   srcs   = (int*)  alloc((size_t)N_EDGES * 4);
    float* pdb    = (float*)alloc((size_t)N_EDGES * 8);
    __half* vv    = (__half*)alloc((size_t)N_NODES * D * 2);
    __half* as_   = (__half*)alloc((size_t)N_NODES * D * 2);
    float* ad     = (float*) alloc((size_t)N_NODES * D * 4);
    float* h0     = (float*) alloc((size_t)N_NODES * D * 4);
    float* h1     = (float*) alloc((size_t)N_NODES * D * 4);
    unsigned short* bpk = (unsigned short*)alloc((size_t)NLAYERS * LSTRIDE * 2);

    // sort edges by dst (counting sort)
    k_zero   <<<256,  256, 0, stream>>>(deg);
    k_hist   <<<4096, 256, 0, stream>>>(ei + N_EDGES, deg);
    k_scan1  <<<256,  256, 0, stream>>>(deg, part, bsum);
    k_scan2  <<<1,    256, 0, stream>>>(bsum, bofs);
    k_scan3  <<<256,  256, 0, stream>>>(part, bofs, off, cursor);
    k_scatter<<<4096, 256, 0, stream>>>(ei, pos, cursor, srcs, pdb);
    k_pack   <<<192,  256, 0, stream>>>(pW2, aW1, aW2, Wl, Ws, Wd, bpk);

    const float* hin = x;
    float* hbuf[2] = { h0, h1 };
    for (int L = 0; L < NLAYERS; ++L){
        float* hout = hbuf[L & 1];
        k_nodegemm<<<N_NODES/64, 256, 0, stream>>>(hin, bpk + (size_t)L*LSTRIDE,
            vv, as_, ad);
        k_edge<<<N_NODES/G, 256, 0, stream>>>(off, srcs, pdb, vv, as_, ad,
            pW1 + (size_t)L*2*D, pb1 + (size_t)L*D, pb2 + (size_t)L*D,
            ab1 + (size_t)L*D, ab2 + (size_t)L*D,
            bpk + (size_t)L*LSTRIDE,
            hout);
        hin = hout;
    }
    k_pool<<<NB, 256, 0, stream>>>(hin, outW, outb, out);
}